// Round 2
// baseline (607.552 us; speedup 1.0000x reference)
//
#include <hip/hip_runtime.h>
#include <hip/hip_bf16.h>
#include <math.h>

// Problem constants (reference: B=64, L=1024, H=64, VOCAB=64)
#define BB 64
#define LL 1024
#define HH 64

typedef float v4f __attribute__((ext_vector_type(4)));

// ---------------------------------------------------------------------------
// Kernel 1: per-token phase.
// block = 256 threads (4 waves), 32 tokens/block, grid = 65536/32 = 2048.
// Computes hn = LN(h + FF(h)), then writes packed stream knv[b][t] =
// [kn(64) | v(64)] (t<1023) plus vthr[b][t] = 0.16*||v||^2 (SQUARED threshold,
// consumed by the scan's sqrt-free gate), or q (t==1023).
// ---------------------------------------------------------------------------
__global__ __launch_bounds__(256, 1)
void token_kernel(const int* __restrict__ seq,
                  const float* __restrict__ embed_W,
                  const float* __restrict__ ff_W1, const float* __restrict__ ff_b1,
                  const float* __restrict__ ff_W2, const float* __restrict__ ff_b2,
                  const float* __restrict__ ln_g, const float* __restrict__ ln_b,
                  const float* __restrict__ kp_W, const float* __restrict__ vp_W,
                  const float* __restrict__ qp_W,
                  float* __restrict__ knv, float* __restrict__ vthr,
                  float* __restrict__ qbuf)
{
    __shared__ __align__(16) float h_s[32][64];    // 8 KB
    __shared__ __align__(16) float t1_s[32][128];  // 16 KB
    __shared__ __align__(16) float hn_s[32][64];   // 8 KB

    const int tid  = threadIdx.x;
    const int tok0 = blockIdx.x * 32;

    // ---- Stage A: embedding gather into LDS ----
#pragma unroll
    for (int k = 0; k < 8; ++k) {
        int e   = k * 256 + tid;
        int tok = e >> 6, i = e & 63;
        int s   = seq[tok0 + tok];
        h_s[tok][i] = embed_W[s * 64 + i];
    }
    __syncthreads();

    // ---- Stage B: FF1 (64 -> 128, ReLU) ----
    {
        const int j = tid & 127;
        const int g = tid >> 7;
        float w1c[64];
#pragma unroll
        for (int ii = 0; ii < 64; ++ii) w1c[ii] = ff_W1[ii * 128 + j];
        const float b1j = ff_b1[j];
#pragma unroll
        for (int tk = 0; tk < 16; ++tk) {
            const int tok = g * 16 + tk;
            const float4* h4 = (const float4*)h_s[tok];
            float a0 = b1j, a1 = 0.f, a2 = 0.f, a3 = 0.f;
#pragma unroll
            for (int w = 0; w < 16; ++w) {
                float4 hv = h4[w];
                a0 = fmaf(hv.x, w1c[4*w+0], a0);
                a1 = fmaf(hv.y, w1c[4*w+1], a1);
                a2 = fmaf(hv.z, w1c[4*w+2], a2);
                a3 = fmaf(hv.w, w1c[4*w+3], a3);
            }
            t1_s[tok][j] = fmaxf((a0 + a1) + (a2 + a3), 0.f);
        }
    }
    __syncthreads();

    // ---- Stage C: FF2 (128 -> 64) + residual + LayerNorm (w2 in 2 halves) ----
    {
        const int i  = tid & 63;
        const int w4 = tid >> 6;
        const float b2i = ff_b2[i];
        const float gi  = ln_g[i];
        const float bi  = ln_b[i];
        float accf[8];
#pragma unroll
        for (int tk = 0; tk < 8; ++tk) accf[tk] = b2i;
#pragma unroll
        for (int h = 0; h < 2; ++h) {
            float w2c[64];
#pragma unroll
            for (int jj = 0; jj < 64; ++jj) w2c[jj] = ff_W2[(h*64 + jj) * 64 + i];
#pragma unroll
            for (int tk = 0; tk < 8; ++tk) {
                const int tok = w4 * 8 + tk;
                const float4* t4 = (const float4*)&t1_s[tok][h*64];
                float a0 = 0.f, a1 = 0.f, a2 = 0.f, a3 = 0.f;
#pragma unroll
                for (int w = 0; w < 16; ++w) {
                    float4 tv = t4[w];
                    a0 = fmaf(tv.x, w2c[4*w+0], a0);
                    a1 = fmaf(tv.y, w2c[4*w+1], a1);
                    a2 = fmaf(tv.z, w2c[4*w+2], a2);
                    a3 = fmaf(tv.w, w2c[4*w+3], a3);
                }
                accf[tk] += (a0 + a1) + (a2 + a3);
            }
        }
#pragma unroll
        for (int tk = 0; tk < 8; ++tk) {
            const int tok = w4 * 8 + tk;
            float x = h_s[tok][i] + accf[tk];
            float s = x;
#pragma unroll
            for (int m = 32; m > 0; m >>= 1) s += __shfl_xor(s, m);
            float mu = s * (1.f / 64.f);
            float d  = x - mu;
            float s2 = d * d;
#pragma unroll
            for (int m = 32; m > 0; m >>= 1) s2 += __shfl_xor(s2, m);
            float var = s2 * (1.f / 64.f);
            hn_s[tok][i] = d / sqrtf(var + 1e-5f) * gi + bi;
        }
    }
    __syncthreads();

    // ---- Stage D: kn/v into packed stream (t<1023) OR q (t==1023) ----
    {
        const int i  = tid & 63;
        const int w4 = tid >> 6;
        float kc[64], vc[64];
#pragma unroll
        for (int ii = 0; ii < 64; ++ii) {
            kc[ii] = kp_W[ii * 64 + i];
            vc[ii] = vp_W[ii * 64 + i];
        }
#pragma unroll
        for (int tk = 0; tk < 8; ++tk) {
            const int tok = w4 * 8 + tk;
            const int tg  = tok0 + tok;
            const int b   = tg >> 10;
            const int t   = tg & 1023;
            const float4* hn4 = (const float4*)hn_s[tok];
            if (t < 1023) {
                float ka0=0.f,ka1=0.f,ka2=0.f,ka3=0.f;
                float va0=0.f,va1=0.f,va2=0.f,va3=0.f;
#pragma unroll
                for (int w = 0; w < 16; ++w) {
                    float4 hv = hn4[w];
                    ka0 = fmaf(hv.x, kc[4*w+0], ka0);
                    ka1 = fmaf(hv.y, kc[4*w+1], ka1);
                    ka2 = fmaf(hv.z, kc[4*w+2], ka2);
                    ka3 = fmaf(hv.w, kc[4*w+3], ka3);
                    va0 = fmaf(hv.x, vc[4*w+0], va0);
                    va1 = fmaf(hv.y, vc[4*w+1], va1);
                    va2 = fmaf(hv.z, vc[4*w+2], va2);
                    va3 = fmaf(hv.w, vc[4*w+3], va3);
                }
                float ka = (ka0 + ka1) + (ka2 + ka3);
                float va = (va0 + va1) + (va2 + va3);
                float kn2 = ka * ka, vn2 = va * va;
#pragma unroll
                for (int m = 32; m > 0; m >>= 1) {
                    kn2 += __shfl_xor(kn2, m);
                    vn2 += __shfl_xor(vn2, m);
                }
                float knorm = fmaxf(sqrtf(kn2), 1e-12f);
                size_t row = ((size_t)b * 1024 + t) * 128;
                knv[row + i]      = ka / knorm;
                knv[row + 64 + i] = va;
                if (i == 0) vthr[b * 1024 + t] = 0.16f * vn2;   // SQUARED threshold
            } else {
                float qa0=0.f,qa1=0.f,qa2=0.f,qa3=0.f;
#pragma unroll
                for (int w = 0; w < 16; ++w) {
                    float4 hv = hn4[w];
                    qa0 = fmaf(hv.x, qp_W[(4*w+0)*64 + i], qa0);
                    qa1 = fmaf(hv.y, qp_W[(4*w+1)*64 + i], qa1);
                    qa2 = fmaf(hv.z, qp_W[(4*w+2)*64 + i], qa2);
                    qa3 = fmaf(hv.w, qp_W[(4*w+3)*64 + i], qa3);
                }
                qbuf[b * 64 + i] = (qa0 + qa1) + (qa2 + qa3);
            }
        }
    }
}

// ---------------------------------------------------------------------------
// Kernel 2: sequential fast-weight scan + output head.
// ONE-STEP LOOKAHEAD + 4-SET REGISTER PIPELINE + BRANCHLESS UPDATE.
//
// Identity: vp_{t+1} = M_t kn_{t+1} = (M_{t-1} kn_{t+1}) + (kn_t . kn_{t+1}) gd_t
//
// Register sets A,B,C,D rotate with period 4: at iter t, the set that held
// kn_{t-2} (dead since the UPD at iter t-1) receives the ds_reads for
// kn_{t+2}; DOT16 consumes a set loaded a FULL iteration earlier, so LDS
// latency is completely hidden. UPD16 is unconditional (gd=0 is an exact
// fp no-op on finite kn), removing the wave-uniform branch + readfirstlane
// so the whole chunk is one straight-line schedulable block.
//
// grid = 64 (one block/batch), block = 64 (one wave). Lane i owns M row i.
// kn/v stream staged through LDS via global_load_lds, TRIPLE-buffered 16-step
// chunks; prefetch depth 2 chunks under counted vmcnt(8).
// ---------------------------------------------------------------------------

template<int CTRL>
__device__ __forceinline__ float dppadd(float x) {
    int y = __builtin_amdgcn_update_dpp(0, __float_as_int(x), CTRL, 0xF, 0xF, true);
    return x + __int_as_float(y);
}

// full-wave (64 lane) sum, result broadcast via readlane 63
__device__ __forceinline__ float wave_sum64(float x) {
    x = dppadd<0x111>(x); x = dppadd<0x112>(x);
    x = dppadd<0x114>(x); x = dppadd<0x118>(x);
    x = dppadd<0x142>(x); x = dppadd<0x143>(x);
    return __int_as_float(__builtin_amdgcn_readlane(__float_as_int(x), 63));
}

#define RPT16(F) F(0) F(1) F(2) F(3) F(4) F(5) F(6) F(7) \
                 F(8) F(9) F(10) F(11) F(12) F(13) F(14) F(15)

#define INITM(i) v4f m##i = {0.f, 0.f, 0.f, 0.f};
#define QFMA(i)  accq = __builtin_elementwise_fma(m##i, qq[i], accq);

// load kn row (broadcast b128 reads) into register set P
#define LOADK16(P, NROW) do { \
    const v4f* kk_ = (const v4f*)(NROW); \
    P##0 = kk_[0];  P##1 = kk_[1];  P##2 = kk_[2];  P##3 = kk_[3]; \
    P##4 = kk_[4];  P##5 = kk_[5];  P##6 = kk_[6];  P##7 = kk_[7]; \
    P##8 = kk_[8];  P##9 = kk_[9];  P##10 = kk_[10]; P##11 = kk_[11]; \
    P##12 = kk_[12]; P##13 = kk_[13]; P##14 = kk_[14]; P##15 = kk_[15]; \
} while (0)

// M += gd_s * P   (rank-1, 64 FMA, unconditional; gd_s==0 is an exact no-op)
#define UPD16(P) do { \
    v4f gv_ = {gd_s, gd_s, gd_s, gd_s}; \
    m0  = __builtin_elementwise_fma(gv_, P##0,  m0 ); \
    m1  = __builtin_elementwise_fma(gv_, P##1,  m1 ); \
    m2  = __builtin_elementwise_fma(gv_, P##2,  m2 ); \
    m3  = __builtin_elementwise_fma(gv_, P##3,  m3 ); \
    m4  = __builtin_elementwise_fma(gv_, P##4,  m4 ); \
    m5  = __builtin_elementwise_fma(gv_, P##5,  m5 ); \
    m6  = __builtin_elementwise_fma(gv_, P##6,  m6 ); \
    m7  = __builtin_elementwise_fma(gv_, P##7,  m7 ); \
    m8  = __builtin_elementwise_fma(gv_, P##8,  m8 ); \
    m9  = __builtin_elementwise_fma(gv_, P##9,  m9 ); \
    m10 = __builtin_elementwise_fma(gv_, P##10, m10); \
    m11 = __builtin_elementwise_fma(gv_, P##11, m11); \
    m12 = __builtin_elementwise_fma(gv_, P##12, m12); \
    m13 = __builtin_elementwise_fma(gv_, P##13, m13); \
    m14 = __builtin_elementwise_fma(gv_, P##14, m14); \
    m15 = __builtin_elementwise_fma(gv_, P##15, m15); \
} while (0)

// base_s = (M . P) per lane (in-lane dot, 64 FMA + horizontal)
#define DOT16(P) do { \
    v4f s0_ = __builtin_elementwise_fma(m0,  P##0, \
              __builtin_elementwise_fma(m4,  P##4, \
              __builtin_elementwise_fma(m8,  P##8,  m12 * P##12))); \
    v4f s1_ = __builtin_elementwise_fma(m1,  P##1, \
              __builtin_elementwise_fma(m5,  P##5, \
              __builtin_elementwise_fma(m9,  P##9,  m13 * P##13))); \
    v4f s2_ = __builtin_elementwise_fma(m2,  P##2, \
              __builtin_elementwise_fma(m6,  P##6, \
              __builtin_elementwise_fma(m10, P##10, m14 * P##14))); \
    v4f s3_ = __builtin_elementwise_fma(m3,  P##3, \
              __builtin_elementwise_fma(m7,  P##7, \
              __builtin_elementwise_fma(m11, P##11, m15 * P##15))); \
    v4f st_ = (s0_ + s1_) + (s2_ + s3_); \
    base_s = (st_.x + st_.y) + (st_.z + st_.w); \
} while (0)

// One pipelined iteration t.
//  entering: set U = kn_{t-1}, set holding kn_t (scalar knl_cur tracks its
//            lane element), set Dst = kn_{t+1} (loaded at iter t-1),
//            set L = free (held kn_{t-2}, dead).
//            base_s = M_{t-2}.kn_t, c_s = kn_{t-1}.kn_t, gd_s = gd_{t-1},
//            vv_s = v_t[lane], t2_s = th2_t; *_nxt hold the t+1 scalars.
//  ROW2 points at the packed row of step t+2; TH2P2 at th2_{t+2}.
#define ITER4(L, U, Dst, ROW2, TH2P2) do { \
    LOADK16(L, ROW2);                       /* kn_{t+2}, full iter of slack */ \
    float knl2_ = (ROW2)[lane]; \
    float vv2_  = (ROW2)[64 + lane]; \
    float t22_  = *(TH2P2); \
    UPD16(U);                               /* M -> M_{t-1} (gd_{t-1}) */ \
    float vp_ = fmaf(c_s, gd_s, base_s); \
    float d_  = vv_s - vp_; \
    float e_  = wave_sum64(d_ * d_); \
    gd_s = (e_ > t2_s) ? d_ : 0.0f; \
    DOT16(Dst);                             /* base_{t+1} = M_{t-1}.kn_{t+1} */ \
    c_s = wave_sum64(knl_cur * knl_nxt);    /* kn_t . kn_{t+1} */ \
    knl_cur = knl_nxt; knl_nxt = knl2_; \
    vv_s = vv_nxt;     vv_nxt = vv2_; \
    t2_s = t2_nxt;     t2_nxt = t22_; \
} while (0)

// 16 iterations, local steps s=0..15 (t = 16c+s). Set pattern has period 4
// and 16c == 0 (mod 4), so every chunk starts at phase (C,D,B).
// Loads at s=14,15 cross into NB (next chunk's buffer).
#define CHUNK16_4(CB, NB, TP) \
    ITER4(C,D,B,(CB)+2*128,(TP)+2);   ITER4(D,A,C,(CB)+3*128,(TP)+3); \
    ITER4(A,B,D,(CB)+4*128,(TP)+4);   ITER4(B,C,A,(CB)+5*128,(TP)+5); \
    ITER4(C,D,B,(CB)+6*128,(TP)+6);   ITER4(D,A,C,(CB)+7*128,(TP)+7); \
    ITER4(A,B,D,(CB)+8*128,(TP)+8);   ITER4(B,C,A,(CB)+9*128,(TP)+9); \
    ITER4(C,D,B,(CB)+10*128,(TP)+10); ITER4(D,A,C,(CB)+11*128,(TP)+11); \
    ITER4(A,B,D,(CB)+12*128,(TP)+12); ITER4(B,C,A,(CB)+13*128,(TP)+13); \
    ITER4(C,D,B,(CB)+14*128,(TP)+14); ITER4(D,A,C,(CB)+15*128,(TP)+15); \
    ITER4(A,B,D,(NB)+0*128,(TP)+16);  ITER4(B,C,A,(NB)+1*128,(TP)+17);

// final 15 iterations: steps t=1008..1022. Lookahead rows 1023/1024 are
// allocated-but-garbage; all results derived from them are unused.
#define CHUNK15_4(CB, NB, TP) \
    ITER4(C,D,B,(CB)+2*128,(TP)+2);   ITER4(D,A,C,(CB)+3*128,(TP)+3); \
    ITER4(A,B,D,(CB)+4*128,(TP)+4);   ITER4(B,C,A,(CB)+5*128,(TP)+5); \
    ITER4(C,D,B,(CB)+6*128,(TP)+6);   ITER4(D,A,C,(CB)+7*128,(TP)+7); \
    ITER4(A,B,D,(CB)+8*128,(TP)+8);   ITER4(B,C,A,(CB)+9*128,(TP)+9); \
    ITER4(C,D,B,(CB)+10*128,(TP)+10); ITER4(D,A,C,(CB)+11*128,(TP)+11); \
    ITER4(A,B,D,(CB)+12*128,(TP)+12); ITER4(B,C,A,(CB)+13*128,(TP)+13); \
    ITER4(C,D,B,(CB)+14*128,(TP)+14); ITER4(D,A,C,(CB)+15*128,(TP)+15); \
    ITER4(A,B,D,(NB)+0*128,(TP)+16);

// async copy: 1024 B contiguous global -> contiguous LDS (one inst)
__device__ __forceinline__ void gl2lds_1k(const float* g, float* l, int lane) {
    __builtin_amdgcn_global_load_lds(
        (const __attribute__((address_space(1))) void*)(g + lane * 4),
        (__attribute__((address_space(3))) void*)l, 16, 0, 0);
}

__device__ __forceinline__ void prefetch_chunk(const float* g, float* l, int lane) {
#pragma unroll
    for (int w = 0; w < 8; ++w)
        gl2lds_1k(g + w * 256, l + w * 256, lane);
}

__global__ __launch_bounds__(64, 1)
void scan_kernel(const float* __restrict__ knv,
                 const float* __restrict__ vthr,
                 const float* __restrict__ qbuf,
                 const float* __restrict__ rp_W, const float* __restrict__ rp_b,
                 const float* __restrict__ out_W, const float* __restrict__ out_b,
                 float* __restrict__ out)
{
    const int b    = blockIdx.x;
    const int lane = threadIdx.x;
    const float* knvb = knv  + (size_t)b * 1024 * 128;
    const float* thrb = vthr + (size_t)b * 1024;

    __shared__ __align__(16) float thr_s[1040];     // th^2 per step (+pad for t+2 peek)
    __shared__ __align__(16) float buf[3 * 2048];   // 3 x 8 KB (16 steps each)
    __shared__ float sh[64];

    RPT16(INITM)

    // four kn register sets (rotate with period 4)
    v4f A0,A1,A2,A3,A4,A5,A6,A7,A8,A9,A10,A11,A12,A13,A14,A15;
    v4f B0,B1,B2,B3,B4,B5,B6,B7,B8,B9,B10,B11,B12,B13,B14,B15;
    v4f C0,C1,C2,C3,C4,C5,C6,C7,C8,C9,C10,C11,C12,C13,C14,C15;
    v4f D0,D1,D2,D3,D4,D5,D6,D7,D8,D9,D10,D11,D12,D13,D14,D15;

    // prefetch: thr (4 insts), chunks 0,1,2 (8 each) -> 28 outstanding
#pragma unroll
    for (int w = 0; w < 4; ++w) gl2lds_1k(thrb + w * 256, thr_s + w * 256, lane);
    prefetch_chunk(knvb,        buf,        lane);
    prefetch_chunk(knvb + 2048, buf + 2048, lane);
    prefetch_chunk(knvb + 4096, buf + 4096, lane);

    // thr + chunk 0 resident (chunks 1,2 = 16 loads still in flight)
    asm volatile("s_waitcnt vmcnt(16)" ::: "memory");

    // D plays kn_{-1} for the (unconditional, gd=0) first UPD -> must be zeros
    {
        v4f z_ = {0.f, 0.f, 0.f, 0.f};
        D0=z_;D1=z_;D2=z_;D3=z_;D4=z_;D5=z_;D6=z_;D7=z_;
        D8=z_;D9=z_;D10=z_;D11=z_;D12=z_;D13=z_;D14=z_;D15=z_;
    }
    LOADK16(A, buf);            // kn_0
    LOADK16(B, buf + 128);      // kn_1
    float knl_cur = buf[lane];          // kn_0[lane]
    float knl_nxt = buf[128 + lane];    // kn_1[lane]
    float vv_s    = buf[64 + lane];     // v_0[lane]
    float vv_nxt  = buf[192 + lane];    // v_1[lane]
    float t2_s    = thr_s[0];
    float t2_nxt  = thr_s[1];
    float gd_s = 0.f, base_s = 0.f, c_s = 0.f;

#pragma unroll 1
    for (int c = 0; c < 62; ++c) {
        // chunks <= c+1 resident; chunk c+2's 8 loads may be in flight
        asm volatile("s_waitcnt vmcnt(8)" ::: "memory");
        const float* cb = buf + (c % 3) * 2048;
        const float* nb = buf + ((c + 1) % 3) * 2048;
        const float* tp = thr_s + c * 16;
        CHUNK16_4(cb, nb, tp)
        if (c <= 60)
            prefetch_chunk(knvb + (size_t)(c + 3) * 2048,
                           buf + (c % 3) * 2048, lane);
    }
    asm volatile("s_waitcnt vmcnt(0)" ::: "memory");
    {   // chunk 62 (buf[2]), lookahead into chunk 63 (buf[0])
        const float* cb = buf + 2 * 2048;
        const float* nb = buf;
        const float* tp = thr_s + 62 * 16;
        CHUNK16_4(cb, nb, tp)
    }
    {   // chunk 63 (buf[0]): steps 1008..1022; dummy NB = buf[1] (valid LDS)
        const float* cb = buf;
        const float* nb = buf + 2048;
        const float* tp = thr_s + 63 * 16;
        CHUNK15_4(cb, nb, tp)
    }
    // final deferred update: M_{1022} = M_{1021} + gd_{1022} kn_{1022}^T
    // (kn_{1022} lives in set C: 1022 mod 4 == 2)
    UPD16(C);

    // ---- output head: vq = M q ; r = vq @ rp_W + rp_b ; out = r @ out_W + out_b
    const v4f* qq = (const v4f*)(qbuf + b * 64);
    v4f accq = {0.f, 0.f, 0.f, 0.f};
    RPT16(QFMA)
    float vq = (accq.x + accq.y) + (accq.z + accq.w);

    sh[lane] = vq;
    __syncthreads();
    float r = rp_b[lane];
#pragma unroll
    for (int ii = 0; ii < 64; ++ii) r = fmaf(sh[ii], rp_W[ii * 64 + lane], r);
    __syncthreads();
    sh[lane] = r;
    __syncthreads();
    float o = out_b[lane];
#pragma unroll
    for (int ii = 0; ii < 64; ++ii) o = fmaf(sh[ii], out_W[ii * 64 + lane], o);
    out[b * 64 + lane] = o;
}

// ---------------------------------------------------------------------------
// Launch. Workspace (fp32): knv[64][1024][128] (33.55 MB, t=1023 row unused) |
// vthr[64][1024] (262 KB) | qbuf[64][64]. Total ~33.9 MB.
// ---------------------------------------------------------------------------
extern "C" void kernel_launch(void* const* d_in, const int* in_sizes, int n_in,
                              void* d_out, int out_size, void* d_ws, size_t ws_size,
                              hipStream_t stream)
{
    const int*   seq   = (const int*)  d_in[0];
    const float* embed = (const float*)d_in[1];
    const float* ffW1  = (const float*)d_in[2];
    const float* ffb1  = (const float*)d_in[3];
    const float* ffW2  = (const float*)d_in[4];
    const float* ffb2  = (const float*)d_in[5];
    const float* lng   = (const float*)d_in[6];
    const float* lnb   = (const float*)d_in[7];
    const float* kpW   = (const float*)d_in[8];
    const float* vpW   = (const float*)d_in[9];
    const float* qpW   = (const float*)d_in[10];
    const float* rpW   = (const float*)d_in[11];
    const float* rpb   = (const float*)d_in[12];
    const float* outW  = (const float*)d_in[13];
    const float* outb  = (const float*)d_in[14];
    float* out = (float*)d_out;

    float* knv  = (float*)d_ws;
    float* vthr = knv  + (size_t)64 * 1024 * 128;
    float* qbuf = vthr + (size_t)64 * 1024;

    token_kernel<<<2048, 256, 0, stream>>>(seq, embed, ffW1, ffb1, ffW2, ffb2,
                                           lng, lnb, kpW, vpW, qpW,
                                           knv, vthr, qbuf);
    scan_kernel<<<64, 64, 0, stream>>>(knv, vthr, qbuf,
                                       rpW, rpb, outW, outb, out);
}

// Round 3
// 435.262 us; speedup vs baseline: 1.3958x; 1.3958x over previous
//
#include <hip/hip_runtime.h>
#include <hip/hip_bf16.h>
#include <math.h>

// Problem constants (reference: B=64, L=1024, H=64, VOCAB=64)
#define BB 64
#define LL 1024
#define HH 64

typedef float v4f __attribute__((ext_vector_type(4)));

// ---------------------------------------------------------------------------
// Kernel 1: per-token phase.
// block = 256 threads (4 waves), 32 tokens/block, grid = 65536/32 = 2048.
// Computes hn = LN(h + FF(h)), then writes packed stream knv[b][t] =
// [kn(64) | v(64)] (t<1023) plus vthr[b][t] = 0.16*||v||^2 (SQUARED threshold,
// consumed by the scan's sqrt-free gate), or q (t==1023).
// ---------------------------------------------------------------------------
__global__ __launch_bounds__(256, 1)
void token_kernel(const int* __restrict__ seq,
                  const float* __restrict__ embed_W,
                  const float* __restrict__ ff_W1, const float* __restrict__ ff_b1,
                  const float* __restrict__ ff_W2, const float* __restrict__ ff_b2,
                  const float* __restrict__ ln_g, const float* __restrict__ ln_b,
                  const float* __restrict__ kp_W, const float* __restrict__ vp_W,
                  const float* __restrict__ qp_W,
                  float* __restrict__ knv, float* __restrict__ vthr,
                  float* __restrict__ qbuf)
{
    __shared__ __align__(16) float h_s[32][64];    // 8 KB
    __shared__ __align__(16) float t1_s[32][128];  // 16 KB
    __shared__ __align__(16) float hn_s[32][64];   // 8 KB

    const int tid  = threadIdx.x;
    const int tok0 = blockIdx.x * 32;

    // ---- Stage A: embedding gather into LDS ----
#pragma unroll
    for (int k = 0; k < 8; ++k) {
        int e   = k * 256 + tid;
        int tok = e >> 6, i = e & 63;
        int s   = seq[tok0 + tok];
        h_s[tok][i] = embed_W[s * 64 + i];
    }
    __syncthreads();

    // ---- Stage B: FF1 (64 -> 128, ReLU) ----
    {
        const int j = tid & 127;
        const int g = tid >> 7;
        float w1c[64];
#pragma unroll
        for (int ii = 0; ii < 64; ++ii) w1c[ii] = ff_W1[ii * 128 + j];
        const float b1j = ff_b1[j];
#pragma unroll
        for (int tk = 0; tk < 16; ++tk) {
            const int tok = g * 16 + tk;
            const float4* h4 = (const float4*)h_s[tok];
            float a0 = b1j, a1 = 0.f, a2 = 0.f, a3 = 0.f;
#pragma unroll
            for (int w = 0; w < 16; ++w) {
                float4 hv = h4[w];
                a0 = fmaf(hv.x, w1c[4*w+0], a0);
                a1 = fmaf(hv.y, w1c[4*w+1], a1);
                a2 = fmaf(hv.z, w1c[4*w+2], a2);
                a3 = fmaf(hv.w, w1c[4*w+3], a3);
            }
            t1_s[tok][j] = fmaxf((a0 + a1) + (a2 + a3), 0.f);
        }
    }
    __syncthreads();

    // ---- Stage C: FF2 (128 -> 64) + residual + LayerNorm (w2 in 2 halves) ----
    {
        const int i  = tid & 63;
        const int w4 = tid >> 6;
        const float b2i = ff_b2[i];
        const float gi  = ln_g[i];
        const float bi  = ln_b[i];
        float accf[8];
#pragma unroll
        for (int tk = 0; tk < 8; ++tk) accf[tk] = b2i;
#pragma unroll
        for (int h = 0; h < 2; ++h) {
            float w2c[64];
#pragma unroll
            for (int jj = 0; jj < 64; ++jj) w2c[jj] = ff_W2[(h*64 + jj) * 64 + i];
#pragma unroll
            for (int tk = 0; tk < 8; ++tk) {
                const int tok = w4 * 8 + tk;
                const float4* t4 = (const float4*)&t1_s[tok][h*64];
                float a0 = 0.f, a1 = 0.f, a2 = 0.f, a3 = 0.f;
#pragma unroll
                for (int w = 0; w < 16; ++w) {
                    float4 tv = t4[w];
                    a0 = fmaf(tv.x, w2c[4*w+0], a0);
                    a1 = fmaf(tv.y, w2c[4*w+1], a1);
                    a2 = fmaf(tv.z, w2c[4*w+2], a2);
                    a3 = fmaf(tv.w, w2c[4*w+3], a3);
                }
                accf[tk] += (a0 + a1) + (a2 + a3);
            }
        }
#pragma unroll
        for (int tk = 0; tk < 8; ++tk) {
            const int tok = w4 * 8 + tk;
            float x = h_s[tok][i] + accf[tk];
            float s = x;
#pragma unroll
            for (int m = 32; m > 0; m >>= 1) s += __shfl_xor(s, m);
            float mu = s * (1.f / 64.f);
            float d  = x - mu;
            float s2 = d * d;
#pragma unroll
            for (int m = 32; m > 0; m >>= 1) s2 += __shfl_xor(s2, m);
            float var = s2 * (1.f / 64.f);
            hn_s[tok][i] = d / sqrtf(var + 1e-5f) * gi + bi;
        }
    }
    __syncthreads();

    // ---- Stage D: kn/v into packed stream (t<1023) OR q (t==1023) ----
    {
        const int i  = tid & 63;
        const int w4 = tid >> 6;
        float kc[64], vc[64];
#pragma unroll
        for (int ii = 0; ii < 64; ++ii) {
            kc[ii] = kp_W[ii * 64 + i];
            vc[ii] = vp_W[ii * 64 + i];
        }
#pragma unroll
        for (int tk = 0; tk < 8; ++tk) {
            const int tok = w4 * 8 + tk;
            const int tg  = tok0 + tok;
            const int b   = tg >> 10;
            const int t   = tg & 1023;
            const float4* hn4 = (const float4*)hn_s[tok];
            if (t < 1023) {
                float ka0=0.f,ka1=0.f,ka2=0.f,ka3=0.f;
                float va0=0.f,va1=0.f,va2=0.f,va3=0.f;
#pragma unroll
                for (int w = 0; w < 16; ++w) {
                    float4 hv = hn4[w];
                    ka0 = fmaf(hv.x, kc[4*w+0], ka0);
                    ka1 = fmaf(hv.y, kc[4*w+1], ka1);
                    ka2 = fmaf(hv.z, kc[4*w+2], ka2);
                    ka3 = fmaf(hv.w, kc[4*w+3], ka3);
                    va0 = fmaf(hv.x, vc[4*w+0], va0);
                    va1 = fmaf(hv.y, vc[4*w+1], va1);
                    va2 = fmaf(hv.z, vc[4*w+2], va2);
                    va3 = fmaf(hv.w, vc[4*w+3], va3);
                }
                float ka = (ka0 + ka1) + (ka2 + ka3);
                float va = (va0 + va1) + (va2 + va3);
                float kn2 = ka * ka, vn2 = va * va;
#pragma unroll
                for (int m = 32; m > 0; m >>= 1) {
                    kn2 += __shfl_xor(kn2, m);
                    vn2 += __shfl_xor(vn2, m);
                }
                float knorm = fmaxf(sqrtf(kn2), 1e-12f);
                size_t row = ((size_t)b * 1024 + t) * 128;
                knv[row + i]      = ka / knorm;
                knv[row + 64 + i] = va;
                if (i == 0) vthr[b * 1024 + t] = 0.16f * vn2;   // SQUARED threshold
            } else {
                float qa0=0.f,qa1=0.f,qa2=0.f,qa3=0.f;
#pragma unroll
                for (int w = 0; w < 16; ++w) {
                    float4 hv = hn4[w];
                    qa0 = fmaf(hv.x, qp_W[(4*w+0)*64 + i], qa0);
                    qa1 = fmaf(hv.y, qp_W[(4*w+1)*64 + i], qa1);
                    qa2 = fmaf(hv.z, qp_W[(4*w+2)*64 + i], qa2);
                    qa3 = fmaf(hv.w, qp_W[(4*w+3)*64 + i], qa3);
                }
                qbuf[b * 64 + i] = (qa0 + qa1) + (qa2 + qa3);
            }
        }
    }
}

// ---------------------------------------------------------------------------
// Kernel 2: sequential fast-weight scan + output head.
// TOP-DOT / CHAIN / BOTTOM-UPD with strict 2-set alternation.
//
// Identity: vp_{t+1} = M_t kn_{t+1} = (M_{t-1} kn_{t+1}) + (kn_t . kn_{t+1}) gd_t
//
// Iter t layout (M = M_{t-1} at entry; A/B sets alternate X/Y roles):
//   TOP    : nbase = M_{t-1} . kn_{t+1}   (set X, loaded at iter t-1 -> LDS
//            latency fully hidden; independent of this step's gate chain)
//   CHAIN  : vp_t = fma(c_t, gd_{t-1}, base_t); d; ||d||^2 DPP-reduce; gate
//   OFF    : c_{t+1} = kn_t . kn_{t+1} (wave reduce of per-lane product)
//   BOTTOM : M += gd_t * kn_t (set Y, branchless)  ->  M = M_t
//            refill Y with kn_{t+2} (consumed at iter t+1's TOP)
//
// The only register-serialized pair is UPD(t) -> DOT(t+1), which is pairwise
// pipelinable per M-register. No deferred final update (M final after t=1022).
//
// grid = 64 (one block/batch), block = 64 (one wave). Lane i owns M row i.
// kn/v stream staged through LDS via global_load_lds, TRIPLE-buffered 16-step
// chunks; prefetch depth 2 chunks under counted vmcnt(8).
// ---------------------------------------------------------------------------

template<int CTRL>
__device__ __forceinline__ float dppadd(float x) {
    int y = __builtin_amdgcn_update_dpp(0, __float_as_int(x), CTRL, 0xF, 0xF, true);
    return x + __int_as_float(y);
}

// full-wave (64 lane) sum, result broadcast via readlane 63
__device__ __forceinline__ float wave_sum64(float x) {
    x = dppadd<0x111>(x); x = dppadd<0x112>(x);
    x = dppadd<0x114>(x); x = dppadd<0x118>(x);
    x = dppadd<0x142>(x); x = dppadd<0x143>(x);
    return __int_as_float(__builtin_amdgcn_readlane(__float_as_int(x), 63));
}

#define RPT16(F) F(0) F(1) F(2) F(3) F(4) F(5) F(6) F(7) \
                 F(8) F(9) F(10) F(11) F(12) F(13) F(14) F(15)

#define INITM(i) v4f m##i = {0.f, 0.f, 0.f, 0.f};
#define QFMA(i)  accq = __builtin_elementwise_fma(m##i, qq[i], accq);

// load kn row (broadcast b128 reads) into register set P
#define LOADK16(P, NROW) do { \
    const v4f* kk_ = (const v4f*)(NROW); \
    P##0 = kk_[0];  P##1 = kk_[1];  P##2 = kk_[2];  P##3 = kk_[3]; \
    P##4 = kk_[4];  P##5 = kk_[5];  P##6 = kk_[6];  P##7 = kk_[7]; \
    P##8 = kk_[8];  P##9 = kk_[9];  P##10 = kk_[10]; P##11 = kk_[11]; \
    P##12 = kk_[12]; P##13 = kk_[13]; P##14 = kk_[14]; P##15 = kk_[15]; \
} while (0)

// M += gd_s * P   (rank-1, branchless; gd_s==0 is an exact fp no-op)
#define UPD16(P) do { \
    v4f gv_ = {gd_s, gd_s, gd_s, gd_s}; \
    m0  = __builtin_elementwise_fma(gv_, P##0,  m0 ); \
    m1  = __builtin_elementwise_fma(gv_, P##1,  m1 ); \
    m2  = __builtin_elementwise_fma(gv_, P##2,  m2 ); \
    m3  = __builtin_elementwise_fma(gv_, P##3,  m3 ); \
    m4  = __builtin_elementwise_fma(gv_, P##4,  m4 ); \
    m5  = __builtin_elementwise_fma(gv_, P##5,  m5 ); \
    m6  = __builtin_elementwise_fma(gv_, P##6,  m6 ); \
    m7  = __builtin_elementwise_fma(gv_, P##7,  m7 ); \
    m8  = __builtin_elementwise_fma(gv_, P##8,  m8 ); \
    m9  = __builtin_elementwise_fma(gv_, P##9,  m9 ); \
    m10 = __builtin_elementwise_fma(gv_, P##10, m10); \
    m11 = __builtin_elementwise_fma(gv_, P##11, m11); \
    m12 = __builtin_elementwise_fma(gv_, P##12, m12); \
    m13 = __builtin_elementwise_fma(gv_, P##13, m13); \
    m14 = __builtin_elementwise_fma(gv_, P##14, m14); \
    m15 = __builtin_elementwise_fma(gv_, P##15, m15); \
} while (0)

// OUT = (M . P) per lane (in-lane dot, 64 FMA + horizontal)
#define DOT16(P, OUT) do { \
    v4f s0_ = __builtin_elementwise_fma(m0,  P##0, \
              __builtin_elementwise_fma(m4,  P##4, \
              __builtin_elementwise_fma(m8,  P##8,  m12 * P##12))); \
    v4f s1_ = __builtin_elementwise_fma(m1,  P##1, \
              __builtin_elementwise_fma(m5,  P##5, \
              __builtin_elementwise_fma(m9,  P##9,  m13 * P##13))); \
    v4f s2_ = __builtin_elementwise_fma(m2,  P##2, \
              __builtin_elementwise_fma(m6,  P##6, \
              __builtin_elementwise_fma(m10, P##10, m14 * P##14))); \
    v4f s3_ = __builtin_elementwise_fma(m3,  P##3, \
              __builtin_elementwise_fma(m7,  P##7, \
              __builtin_elementwise_fma(m11, P##11, m15 * P##15))); \
    v4f st_ = (s0_ + s1_) + (s2_ + s3_); \
    OUT = (st_.x + st_.y) + (st_.z + st_.w); \
} while (0)

// One iteration t.  X = kn_{t+1} (DOT source), Y = kn_t (UPD source, then
// refilled with kn_{t+2} from ROW2).  Scalars at entry:
//   base_s = M_{t-1}.kn_t, c_s = kn_{t-1}.kn_t, gd_s = gd_{t-1},
//   vv_s = v_t[lane], t2_s = th2_t, knl_cur = kn_t[lane],
//   knl_nxt = kn_{t+1}[lane], vv_nxt = v_{t+1}[lane], t2_nxt = th2_{t+1}.
#define ITER2(X, Y, ROW2, TH2P2) do { \
    float nbase_; \
    DOT16(X, nbase_);                       /* M_{t-1}.kn_{t+1} (X ready) */ \
    float knl2_ = (ROW2)[lane]; \
    float vv2_  = (ROW2)[64 + lane]; \
    float t22_  = *(TH2P2); \
    float vp_ = fmaf(c_s, gd_s, base_s);    /* chain: step t */ \
    float d_  = vv_s - vp_; \
    float e_  = wave_sum64(d_ * d_); \
    gd_s = (e_ > t2_s) ? d_ : 0.0f;         /* gd_t */ \
    float cn_ = wave_sum64(knl_cur * knl_nxt);  /* kn_t.kn_{t+1}, off-chain */ \
    UPD16(Y);                               /* M -> M_t (gd_t, branchless) */ \
    LOADK16(Y, ROW2);                       /* Y <- kn_{t+2} */ \
    base_s = nbase_;  c_s = cn_; \
    knl_cur = knl_nxt; knl_nxt = knl2_; \
    vv_s = vv_nxt;     vv_nxt = vv2_; \
    t2_s = t2_nxt;     t2_nxt = t22_; \
} while (0)

// 16 iterations, local steps s=0..15 (t = 16c+s).  A/B alternate; 16 even ->
// same phase at every chunk entry (A = kn_{16c+1}, B = kn_{16c}).
// ROW2 = row s+2: s=14 -> NB row 0, s=15 -> NB row 1.
#define CHUNK16_2(CB, NB, TP) \
    ITER2(A,B,(CB)+2*128,(TP)+2);   ITER2(B,A,(CB)+3*128,(TP)+3); \
    ITER2(A,B,(CB)+4*128,(TP)+4);   ITER2(B,A,(CB)+5*128,(TP)+5); \
    ITER2(A,B,(CB)+6*128,(TP)+6);   ITER2(B,A,(CB)+7*128,(TP)+7); \
    ITER2(A,B,(CB)+8*128,(TP)+8);   ITER2(B,A,(CB)+9*128,(TP)+9); \
    ITER2(A,B,(CB)+10*128,(TP)+10); ITER2(B,A,(CB)+11*128,(TP)+11); \
    ITER2(A,B,(CB)+12*128,(TP)+12); ITER2(B,A,(CB)+13*128,(TP)+13); \
    ITER2(A,B,(CB)+14*128,(TP)+14); ITER2(B,A,(CB)+15*128,(TP)+15); \
    ITER2(A,B,(NB)+0*128,(TP)+16);  ITER2(B,A,(NB)+1*128,(TP)+17);

// final 15 iterations: steps t=1008..1022.  Rows 1023 (CB row 15) and 1024
// (NB row 0, dummy) feed only lookahead values whose consumers never run.
#define CHUNK15_2(CB, NB, TP) \
    ITER2(A,B,(CB)+2*128,(TP)+2);   ITER2(B,A,(CB)+3*128,(TP)+3); \
    ITER2(A,B,(CB)+4*128,(TP)+4);   ITER2(B,A,(CB)+5*128,(TP)+5); \
    ITER2(A,B,(CB)+6*128,(TP)+6);   ITER2(B,A,(CB)+7*128,(TP)+7); \
    ITER2(A,B,(CB)+8*128,(TP)+8);   ITER2(B,A,(CB)+9*128,(TP)+9); \
    ITER2(A,B,(CB)+10*128,(TP)+10); ITER2(B,A,(CB)+11*128,(TP)+11); \
    ITER2(A,B,(CB)+12*128,(TP)+12); ITER2(B,A,(CB)+13*128,(TP)+13); \
    ITER2(A,B,(CB)+14*128,(TP)+14); ITER2(B,A,(CB)+15*128,(TP)+15); \
    ITER2(A,B,(NB)+0*128,(TP)+16);

// async copy: 1024 B contiguous global -> contiguous LDS (one inst)
__device__ __forceinline__ void gl2lds_1k(const float* g, float* l, int lane) {
    __builtin_amdgcn_global_load_lds(
        (const __attribute__((address_space(1))) void*)(g + lane * 4),
        (__attribute__((address_space(3))) void*)l, 16, 0, 0);
}

__device__ __forceinline__ void prefetch_chunk(const float* g, float* l, int lane) {
#pragma unroll
    for (int w = 0; w < 8; ++w)
        gl2lds_1k(g + w * 256, l + w * 256, lane);
}

__global__ __launch_bounds__(64, 1)
void scan_kernel(const float* __restrict__ knv,
                 const float* __restrict__ vthr,
                 const float* __restrict__ qbuf,
                 const float* __restrict__ rp_W, const float* __restrict__ rp_b,
                 const float* __restrict__ out_W, const float* __restrict__ out_b,
                 float* __restrict__ out)
{
    const int b    = blockIdx.x;
    const int lane = threadIdx.x;
    const float* knvb = knv  + (size_t)b * 1024 * 128;
    const float* thrb = vthr + (size_t)b * 1024;

    __shared__ __align__(16) float thr_s[1040];     // th^2 per step (+pad for peek)
    __shared__ __align__(16) float buf[3 * 2048];   // 3 x 8 KB (16 steps each)
    __shared__ float sh[64];

    RPT16(INITM)

    // two kn register sets, strict alternation
    v4f A0,A1,A2,A3,A4,A5,A6,A7,A8,A9,A10,A11,A12,A13,A14,A15;
    v4f B0,B1,B2,B3,B4,B5,B6,B7,B8,B9,B10,B11,B12,B13,B14,B15;

    // prefetch: thr (4 insts), chunks 0,1,2 (8 each) -> 28 outstanding
#pragma unroll
    for (int w = 0; w < 4; ++w) gl2lds_1k(thrb + w * 256, thr_s + w * 256, lane);
    prefetch_chunk(knvb,        buf,        lane);
    prefetch_chunk(knvb + 2048, buf + 2048, lane);
    prefetch_chunk(knvb + 4096, buf + 4096, lane);

    // thr + chunk 0 resident (chunks 1,2 = 16 loads still in flight)
    asm volatile("s_waitcnt vmcnt(16)" ::: "memory");

    // prologue (t=0): M_{-1}=0 -> base_0=0, c_0=0, gd_{-1}=0
    LOADK16(B, buf);            // kn_0 (Y at iter 0)
    LOADK16(A, buf + 128);      // kn_1 (X at iter 0)
    float knl_cur = buf[lane];          // kn_0[lane]
    float knl_nxt = buf[128 + lane];    // kn_1[lane]
    float vv_s    = buf[64 + lane];     // v_0[lane]
    float vv_nxt  = buf[192 + lane];    // v_1[lane]
    float t2_s    = thr_s[0];
    float t2_nxt  = thr_s[1];
    float gd_s = 0.f, base_s = 0.f, c_s = 0.f;

#pragma unroll 1
    for (int c = 0; c < 62; ++c) {
        // chunks <= c+1 resident; chunk c+2's 8 loads may be in flight
        asm volatile("s_waitcnt vmcnt(8)" ::: "memory");
        const float* cb = buf + (c % 3) * 2048;
        const float* nb = buf + ((c + 1) % 3) * 2048;
        const float* tp = thr_s + c * 16;
        CHUNK16_2(cb, nb, tp)
        if (c <= 60)
            prefetch_chunk(knvb + (size_t)(c + 3) * 2048,
                           buf + (c % 3) * 2048, lane);
    }
    asm volatile("s_waitcnt vmcnt(0)" ::: "memory");
    {   // chunk 62 (buf[2]), lookahead into chunk 63 (buf[0])
        const float* cb = buf + 2 * 2048;
        const float* nb = buf;
        const float* tp = thr_s + 62 * 16;
        CHUNK16_2(cb, nb, tp)
    }
    {   // chunk 63 (buf[0]): steps 1008..1022; dummy NB = buf[1] (valid LDS)
        const float* cb = buf;
        const float* nb = buf + 2048;
        const float* tp = thr_s + 63 * 16;
        CHUNK15_2(cb, nb, tp)
    }
    // M is final here: iter t=1022 applied gd_1022 * kn_1022 at its bottom.

    // ---- output head: vq = M q ; r = vq @ rp_W + rp_b ; out = r @ out_W + out_b
    const v4f* qq = (const v4f*)(qbuf + b * 64);
    v4f accq = {0.f, 0.f, 0.f, 0.f};
    RPT16(QFMA)
    float vq = (accq.x + accq.y) + (accq.z + accq.w);

    sh[lane] = vq;
    __syncthreads();
    float r = rp_b[lane];
#pragma unroll
    for (int ii = 0; ii < 64; ++ii) r = fmaf(sh[ii], rp_W[ii * 64 + lane], r);
    __syncthreads();
    sh[lane] = r;
    __syncthreads();
    float o = out_b[lane];
#pragma unroll
    for (int ii = 0; ii < 64; ++ii) o = fmaf(sh[ii], out_W[ii * 64 + lane], o);
    out[b * 64 + lane] = o;
}

// ---------------------------------------------------------------------------
// Launch. Workspace (fp32): knv[64][1024][128] (33.55 MB, t=1023 row unused) |
// vthr[64][1024] (262 KB) | qbuf[64][64]. Total ~33.9 MB.
// ---------------------------------------------------------------------------
extern "C" void kernel_launch(void* const* d_in, const int* in_sizes, int n_in,
                              void* d_out, int out_size, void* d_ws, size_t ws_size,
                              hipStream_t stream)
{
    const int*   seq   = (const int*)  d_in[0];
    const float* embed = (const float*)d_in[1];
    const float* ffW1  = (const float*)d_in[2];
    const float* ffb1  = (const float*)d_in[3];
    const float* ffW2  = (const float*)d_in[4];
    const float* ffb2  = (const float*)d_in[5];
    const float* lng   = (const float*)d_in[6];
    const float* lnb   = (const float*)d_in[7];
    const float* kpW   = (const float*)d_in[8];
    const float* vpW   = (const float*)d_in[9];
    const float* qpW   = (const float*)d_in[10];
    const float* rpW   = (const float*)d_in[11];
    const float* rpb   = (const float*)d_in[12];
    const float* outW  = (const float*)d_in[13];
    const float* outb  = (const float*)d_in[14];
    float* out = (float*)d_out;

    float* knv  = (float*)d_ws;
    float* vthr = knv  + (size_t)64 * 1024 * 128;
    float* qbuf = vthr + (size_t)64 * 1024;

    token_kernel<<<2048, 256, 0, stream>>>(seq, embed, ffW1, ffb1, ffW2, ffb2,
                                           lng, lnb, kpW, vpW, qpW,
                                           knv, vthr, qbuf);
    scan_kernel<<<64, 64, 0, stream>>>(knv, vthr, qbuf,
                                       rpW, rpb, outW, outb, out);
}